// Round 7
// baseline (905.119 us; speedup 1.0000x reference)
//
#include <hip/hip_runtime.h>

#define INCH 128
#define C1   16
#define C2   64
#define LOCB 7                   // log2(nodes per bucket)
#define BNODES (1 << LOCB)       // 128 nodes per bucket
#define CAP  5120                // edge capacity per bucket (mean 4096, +16 sigma)
#define ROWBITS 17
#define ROWMASK ((1 << ROWBITS) - 1)

// ---------------- binit: gcur[b] = b*CAP -----------------------------------
__global__ void binit_kernel(int* __restrict__ gcur, int K) {
    int t = blockIdx.x * blockDim.x + threadIdx.x;
    if (t < K) gcur[t] = t * CAP;
}

// ---------------- bucket edges by dst range --------------------------------
// Per-edge RMWs in LDS; one global reservation atomic per (block,bucket).
// barr[slot] = src | (dst_local << 17). Both passes filter edges identically
// so reserved slot count == written slot count (no poison can be read back).
__global__ __launch_bounds__(256) void bucket_kernel(
    const int* __restrict__ row, const int* __restrict__ col,
    int* __restrict__ gcur, int* __restrict__ barr,
    int e, int n, int K, int nblocks)
{
    __shared__ int cnt[1024];
    __shared__ int cur[1024];
    long b0 = (long)blockIdx.x * e / nblocks;
    long b1 = (long)(blockIdx.x + 1) * e / nblocks;
    for (int i = threadIdx.x; i < 1024; i += 256) cnt[i] = 0;
    __syncthreads();
    for (long i = b0 + threadIdx.x; i < b1; i += 256) {
        unsigned c = (unsigned)col[i];
        unsigned r = (unsigned)row[i];
        if (c < (unsigned)n && r < (unsigned)n)
            atomicAdd(&cnt[c >> LOCB], 1);
    }
    __syncthreads();
    for (int i = threadIdx.x; i < K; i += 256) {
        int c = cnt[i];
        cur[i] = c ? atomicAdd(&gcur[i], c) : 0;
    }
    __syncthreads();
    for (long i = b0 + threadIdx.x; i < b1; i += 256) {
        unsigned c = (unsigned)col[i];
        unsigned r = (unsigned)row[i];
        if (c < (unsigned)n && r < (unsigned)n) {
            int b = c >> LOCB;                       // < K since c < n
            int slot = atomicAdd(&cur[b], 1);        // LDS
            if ((unsigned)slot < (unsigned)((b + 1) * CAP))
                barr[slot] = (int)(r | ((c & (BNODES - 1)) << ROWBITS));
        }
    }
}

// ---------------- per-bucket degree -> inv_sqrt ----------------------------
__global__ __launch_bounds__(256) void deg_inv_kernel(
    const int* __restrict__ barr, const int* __restrict__ gcur,
    float* __restrict__ inv, int n)
{
    __shared__ int cnt[BNODES];
    int b = blockIdx.x;
    if (threadIdx.x < BNODES) cnt[threadIdx.x] = 0;
    __syncthreads();
    int base = b * CAP;
    int len = gcur[b] - base;
    if (len > CAP) len = CAP;
    for (int i = threadIdx.x; i < len; i += 256) {
        unsigned pk = (unsigned)barr[base + i];
        atomicAdd(&cnt[(pk >> ROWBITS) & (BNODES - 1)], 1);
    }
    __syncthreads();
    if (threadIdx.x < BNODES) {
        int node = (b << LOCB) + threadIdx.x;
        if (node < n) inv[node] = rsqrtf((float)(cnt[threadIdx.x] + 1));
    }
}

// ---------------- linear1: xW1s = (x@W1)*inv, xT1 = x@t1_W + t1_b ----------
__global__ __launch_bounds__(256) void linear1_kernel(
    const float* __restrict__ x, const float* __restrict__ W1,
    const float* __restrict__ T1, const float* __restrict__ t1b,
    const float* __restrict__ inv,
    float* __restrict__ xW1s, float* __restrict__ xT1, int n)
{
    __shared__ float Wc[INCH][32];        // [:,0:16]=W1, [:,16:32]=t1_W
    __shared__ float xs[16][INCH + 4];
    int tid = threadIdx.x;

    for (int i = tid; i < INCH * C1; i += 256) {
        int k = i / C1, c = i % C1;
        Wc[k][c]      = W1[i];
        Wc[k][c + 16] = T1[i];
    }
    int node0 = blockIdx.x * 16;
    for (int i = tid; i < 16 * (INCH / 4); i += 256) {
        int r = i / (INCH / 4);
        int cc = i % (INCH / 4);
        int node = node0 + r;
        float4 v = make_float4(0.f, 0.f, 0.f, 0.f);
        if (node < n) v = ((const float4*)x)[(size_t)node * (INCH / 4) + cc];
        ((float4*)&xs[r][0])[cc] = v;
    }
    __syncthreads();

    int ch = tid & 15, nl = tid >> 4;
    int node = node0 + nl;
    if (node >= n) return;
    float a1 = 0.f, a2 = 0.f;
    #pragma unroll
    for (int k = 0; k < INCH; ++k) {
        float xv = xs[nl][k];
        a1 += xv * Wc[k][ch];
        a2 += xv * Wc[k][ch + 16];
    }
    xW1s[node * C1 + ch] = a1 * inv[node];   // pre-scaled by inv[src]
    xT1[node * C1 + ch]  = a2 + t1b[ch];
}

// ---------------- agg1: per-bucket LDS accumulate + fused epilogue1 --------
// 16 lanes per edge-group; LDS float atomics (on-CU, no fabric traffic).
__global__ __launch_bounds__(256) void agg1_kernel(
    const int* __restrict__ barr, const int* __restrict__ gcur,
    const float* __restrict__ inv,
    const float* __restrict__ xW1s, const float* __restrict__ xT1,
    const float* __restrict__ b1,
    float* __restrict__ h, float* __restrict__ hs, int n)
{
    __shared__ float acc[BNODES * C1];    // 8 KB
    int b = blockIdx.x;
    for (int i = threadIdx.x; i < BNODES * C1; i += 256) acc[i] = 0.f;
    __syncthreads();
    int base = b * CAP;
    int len = gcur[b] - base;
    if (len > CAP) len = CAP;
    int g = threadIdx.x >> 4, ch = threadIdx.x & 15;
    int i = g;
    for (; i + 48 < len; i += 64) {        // 4-way unroll: 4 gathers in flight
        unsigned pk0 = (unsigned)barr[base + i];
        unsigned pk1 = (unsigned)barr[base + i + 16];
        unsigned pk2 = (unsigned)barr[base + i + 32];
        unsigned pk3 = (unsigned)barr[base + i + 48];
        float v0 = xW1s[((pk0 & ROWMASK) << 4) + ch];
        float v1 = xW1s[((pk1 & ROWMASK) << 4) + ch];
        float v2 = xW1s[((pk2 & ROWMASK) << 4) + ch];
        float v3 = xW1s[((pk3 & ROWMASK) << 4) + ch];
        atomicAdd(&acc[(((pk0 >> ROWBITS) & (BNODES - 1)) << 4) + ch], v0);
        atomicAdd(&acc[(((pk1 >> ROWBITS) & (BNODES - 1)) << 4) + ch], v1);
        atomicAdd(&acc[(((pk2 >> ROWBITS) & (BNODES - 1)) << 4) + ch], v2);
        atomicAdd(&acc[(((pk3 >> ROWBITS) & (BNODES - 1)) << 4) + ch], v3);
    }
    for (; i < len; i += 16) {
        unsigned pk = (unsigned)barr[base + i];
        atomicAdd(&acc[(((pk >> ROWBITS) & (BNODES - 1)) << 4) + ch],
                  xW1s[((pk & ROWMASK) << 4) + ch]);
    }
    __syncthreads();
    for (int j = threadIdx.x; j < BNODES * C1; j += 256) {
        int loc = j >> 4, cch = j & 15;
        int node = (b << LOCB) + loc;
        if (node >= n) continue;
        float ic = inv[node];
        int idx = (node << 4) + cch;
        float v = (acc[j] + xW1s[idx]) * ic + b1[cch];
        float hv = fmaxf(v, 0.f) + xT1[idx];
        h[idx]  = hv;
        hs[idx] = hv * ic;
    }
}

// ---------------- agg2: per-bucket LDS accumulate + 16->64 linears + epi ---
__global__ __launch_bounds__(256) void agg2_kernel(
    const int* __restrict__ barr, const int* __restrict__ gcur,
    const float* __restrict__ inv,
    const float* __restrict__ hs, const float* __restrict__ h,
    const float* __restrict__ W2, const float* __restrict__ T2,
    const float* __restrict__ b2, const float* __restrict__ t2b,
    float* __restrict__ out, int n)
{
    __shared__ float acc[BNODES * C1];    // 8 KB: agg, then aggT in place
    __shared__ float hv_s[BNODES * C1];   // 8 KB: h for identity2
    __shared__ float Wc[C1 * 128];        // 8 KB: [:,0:64]=W2, [:,64:128]=t2_W
    int b = blockIdx.x;
    for (int i = threadIdx.x; i < C1 * 128; i += 256) {
        int k = i >> 7, c = i & 127;
        Wc[i] = (c < 64) ? W2[k * C2 + c] : T2[k * C2 + (c - 64)];
    }
    for (int i = threadIdx.x; i < BNODES * C1; i += 256) acc[i] = 0.f;
    __syncthreads();
    int base = b * CAP;
    int len = gcur[b] - base;
    if (len > CAP) len = CAP;
    int g = threadIdx.x >> 4, ch = threadIdx.x & 15;
    int i = g;
    for (; i + 48 < len; i += 64) {
        unsigned pk0 = (unsigned)barr[base + i];
        unsigned pk1 = (unsigned)barr[base + i + 16];
        unsigned pk2 = (unsigned)barr[base + i + 32];
        unsigned pk3 = (unsigned)barr[base + i + 48];
        float v0 = hs[((pk0 & ROWMASK) << 4) + ch];
        float v1 = hs[((pk1 & ROWMASK) << 4) + ch];
        float v2 = hs[((pk2 & ROWMASK) << 4) + ch];
        float v3 = hs[((pk3 & ROWMASK) << 4) + ch];
        atomicAdd(&acc[(((pk0 >> ROWBITS) & (BNODES - 1)) << 4) + ch], v0);
        atomicAdd(&acc[(((pk1 >> ROWBITS) & (BNODES - 1)) << 4) + ch], v1);
        atomicAdd(&acc[(((pk2 >> ROWBITS) & (BNODES - 1)) << 4) + ch], v2);
        atomicAdd(&acc[(((pk3 >> ROWBITS) & (BNODES - 1)) << 4) + ch], v3);
    }
    for (; i < len; i += 16) {
        unsigned pk = (unsigned)barr[base + i];
        atomicAdd(&acc[(((pk >> ROWBITS) & (BNODES - 1)) << 4) + ch],
                  hs[((pk & ROWMASK) << 4) + ch]);
    }
    __syncthreads();
    // phase A: aggT = (acc + hs[self]) * inv ; stage h for identity
    for (int j = threadIdx.x; j < BNODES * C1; j += 256) {
        int loc = j >> 4, cch = j & 15;
        int node = (b << LOCB) + loc;
        if (node >= n) { acc[j] = 0.f; hv_s[j] = 0.f; continue; }
        int idx = (node << 4) + cch;
        acc[j]  = (acc[j] + hs[idx]) * inv[node];
        hv_s[j] = h[idx];
    }
    __syncthreads();
    // phase B: out = relu(aggT@W2 + b2) + h@t2_W + t2b
    int och = threadIdx.x & 63, set = threadIdx.x >> 6;
    float bb = b2[och], tb = t2b[och];
    for (int loc = set; loc < BNODES; loc += 4) {
        int node = (b << LOCB) + loc;
        if (node >= n) continue;
        float s1 = bb, s2 = tb;
        #pragma unroll
        for (int k = 0; k < C1; ++k) {
            s1 += acc[(loc << 4) + k]  * Wc[(k << 7) + och];
            s2 += hv_s[(loc << 4) + k] * Wc[(k << 7) + 64 + och];
        }
        out[node * C2 + och] = fmaxf(s1, 0.f) + s2;
    }
}

extern "C" void kernel_launch(void* const* d_in, const int* in_sizes, int n_in,
                              void* d_out, int out_size, void* d_ws, size_t ws_size,
                              hipStream_t stream) {
    const float* x   = (const float*)d_in[0];
    const int*   ei  = (const int*)d_in[1];
    const float* W1  = (const float*)d_in[2];
    const float* b1  = (const float*)d_in[3];
    const float* W2  = (const float*)d_in[4];
    const float* b2  = (const float*)d_in[5];
    const float* T1  = (const float*)d_in[6];
    const float* t1b = (const float*)d_in[7];
    const float* T2  = (const float*)d_in[8];
    const float* t2b = (const float*)d_in[9];
    float* out = (float*)d_out;

    const int n = in_sizes[0] / INCH;       // 100000
    const int e = in_sizes[1] / 2;          // 3200000
    const int* row = ei;
    const int* col = ei + e;
    const int K = (n + BNODES - 1) >> LOCB; // 782 buckets

    // workspace layout — barr LAST so any bounded-but-stale gather index
    // (max 2^17*16 floats past a table base) stays inside our allocation.
    char* ws = (char*)d_ws;
    int*   gcur = (int*)ws;                           ws += 4096;
    float* inv  = (float*)ws;                         ws += (size_t)n * 4;
    float* xW1s = (float*)ws;                         ws += (size_t)n * C1 * 4;
    float* xT1  = (float*)ws;                         ws += (size_t)n * C1 * 4;
    float* h    = (float*)ws;                         ws += (size_t)n * C1 * 4;
    float* hs   = (float*)ws;                         ws += (size_t)n * C1 * 4;
    int*   barr = (int*)ws;                           ws += (size_t)K * CAP * 4;  // 16 MB

    const int B = 256;
    const int nbb = 390;     // bucket_kernel blocks

    binit_kernel  <<<(K + B - 1) / B, B, 0, stream>>>(gcur, K);
    bucket_kernel <<<nbb, B, 0, stream>>>(row, col, gcur, barr, e, n, K, nbb);
    deg_inv_kernel<<<K, B, 0, stream>>>(barr, gcur, inv, n);

    linear1_kernel<<<(n + 15) / 16, B, 0, stream>>>(x, W1, T1, t1b, inv, xW1s, xT1, n);
    agg1_kernel   <<<K, B, 0, stream>>>(barr, gcur, inv, xW1s, xT1, b1, h, hs, n);
    agg2_kernel   <<<K, B, 0, stream>>>(barr, gcur, inv, hs, h, W2, T2, b2, t2b, out, n);
}

// Round 8
// 347.748 us; speedup vs baseline: 2.6028x; 2.6028x over previous
//
#include <hip/hip_runtime.h>

#define INCH 128
#define C1   16
#define C2   64
#define LOCB 7                   // log2(nodes per bucket)
#define BNODES (1 << LOCB)       // 128 nodes per bucket
#define CAP  5120                // edge capacity per bucket (mean 4096, +16 sigma)
#define ROWBITS 17
#define ROWMASK ((1 << ROWBITS) - 1)

// ---------------- binit: gcur[b] = b*CAP -----------------------------------
__global__ void binit_kernel(int* __restrict__ gcur, int K) {
    int t = blockIdx.x * blockDim.x + threadIdx.x;
    if (t < K) gcur[t] = t * CAP;
}

// ---------------- bucket edges by dst range (R7, proven) -------------------
// Per-edge RMWs in LDS; ~305k global reservation atomics total.
// barr[slot] = src | (dst_local << 17)
__global__ __launch_bounds__(256) void bucket_kernel(
    const int* __restrict__ row, const int* __restrict__ col,
    int* __restrict__ gcur, int* __restrict__ barr,
    int e, int n, int K, int nblocks)
{
    __shared__ int cnt[1024];
    __shared__ int cur[1024];
    long b0 = (long)blockIdx.x * e / nblocks;
    long b1 = (long)(blockIdx.x + 1) * e / nblocks;
    for (int i = threadIdx.x; i < 1024; i += 256) cnt[i] = 0;
    __syncthreads();
    for (long i = b0 + threadIdx.x; i < b1; i += 256) {
        unsigned c = (unsigned)col[i];
        unsigned r = (unsigned)row[i];
        if (c < (unsigned)n && r < (unsigned)n)
            atomicAdd(&cnt[c >> LOCB], 1);
    }
    __syncthreads();
    for (int i = threadIdx.x; i < K; i += 256) {
        int c = cnt[i];
        cur[i] = c ? atomicAdd(&gcur[i], c) : 0;
    }
    __syncthreads();
    for (long i = b0 + threadIdx.x; i < b1; i += 256) {
        unsigned c = (unsigned)col[i];
        unsigned r = (unsigned)row[i];
        if (c < (unsigned)n && r < (unsigned)n) {
            int b = c >> LOCB;
            int slot = atomicAdd(&cur[b], 1);        // LDS
            if ((unsigned)slot < (unsigned)((b + 1) * CAP))
                barr[slot] = (int)(r | ((c & (BNODES - 1)) << ROWBITS));
        }
    }
}

// ---------------- exclusive scan of bucket lengths -> bbase ----------------
__global__ __launch_bounds__(1024) void bucket_scan_kernel(
    const int* __restrict__ gcur, int* __restrict__ bbase, int K)
{
    __shared__ int tmp[1024];
    int t = threadIdx.x;
    int len = 0;
    if (t < K) {
        int l = gcur[t] - t * CAP;
        len = (l < 0) ? 0 : (l > CAP ? CAP : l);
    }
    tmp[t] = len;
    __syncthreads();
    for (int off = 1; off < 1024; off <<= 1) {
        int v = (t >= off) ? tmp[t - off] : 0;
        __syncthreads();
        tmp[t] += v;
        __syncthreads();
    }
    if (t < K) bbase[t] = tmp[t] - len;   // exclusive
}

// ---------------- per-bucket counting sort -> global CSR -------------------
// One block per bucket. All per-edge RMWs in LDS; sorted writes land in a
// contiguous ~len*4 B window at bbase[b]. Also emits cnt/offs/inv.
__global__ __launch_bounds__(256) void sort_kernel(
    const int* __restrict__ barr, const int* __restrict__ gcur,
    const int* __restrict__ bbase,
    int* __restrict__ cnt, int* __restrict__ offs, float* __restrict__ inv,
    int* __restrict__ sorted, int n)
{
    __shared__ int lcnt[BNODES];
    __shared__ int lcur[BNODES];
    __shared__ int tmp[BNODES];
    int b = blockIdx.x;
    int tid = threadIdx.x;
    if (tid < BNODES) lcnt[tid] = 0;
    __syncthreads();
    int base = b * CAP;
    int len = gcur[b] - base;
    if (len < 0) len = 0;
    if (len > CAP) len = CAP;
    for (int i = tid; i < len; i += 256) {
        unsigned pk = (unsigned)barr[base + i];
        atomicAdd(&lcnt[(pk >> ROWBITS) & (BNODES - 1)], 1);
    }
    __syncthreads();
    // inclusive Hillis-Steele over 128 bins (all 256 threads hit barriers)
    int v = (tid < BNODES) ? lcnt[tid] : 0;
    if (tid < BNODES) tmp[tid] = v;
    __syncthreads();
    for (int off = 1; off < BNODES; off <<= 1) {
        int t2 = (tid < BNODES && tid >= off) ? tmp[tid - off] : 0;
        __syncthreads();
        if (tid < BNODES) tmp[tid] += t2;
        __syncthreads();
    }
    int gbase = bbase[b];
    if (tid < BNODES) {
        int exc = tmp[tid] - v;
        lcur[tid] = exc;
        int node = (b << LOCB) + tid;
        if (node < n) {
            cnt[node]  = v;
            offs[node] = gbase + exc;
            inv[node]  = rsqrtf((float)(v + 1));
        }
    }
    __syncthreads();
    for (int i = tid; i < len; i += 256) {
        unsigned pk = (unsigned)barr[base + i];
        int loc = (pk >> ROWBITS) & (BNODES - 1);
        int pos = atomicAdd(&lcur[loc], 1);          // LDS
        if ((unsigned)pos < (unsigned)CAP * 782u)    // always true; keeps index bounded
            sorted[gbase + pos] = (int)(pk & ROWMASK);
    }
}

// ---------------- linear1: xW1s = (x@W1)*inv, xT1 = x@t1_W + t1_b ----------
__global__ __launch_bounds__(256) void linear1_kernel(
    const float* __restrict__ x, const float* __restrict__ W1,
    const float* __restrict__ T1, const float* __restrict__ t1b,
    const float* __restrict__ inv,
    float* __restrict__ xW1s, float* __restrict__ xT1, int n)
{
    __shared__ float Wc[INCH][32];        // [:,0:16]=W1, [:,16:32]=t1_W
    __shared__ float xs[16][INCH + 4];
    int tid = threadIdx.x;

    for (int i = tid; i < INCH * C1; i += 256) {
        int k = i / C1, c = i % C1;
        Wc[k][c]      = W1[i];
        Wc[k][c + 16] = T1[i];
    }
    int node0 = blockIdx.x * 16;
    for (int i = tid; i < 16 * (INCH / 4); i += 256) {
        int r = i / (INCH / 4);
        int cc = i % (INCH / 4);
        int node = node0 + r;
        float4 v = make_float4(0.f, 0.f, 0.f, 0.f);
        if (node < n) v = ((const float4*)x)[(size_t)node * (INCH / 4) + cc];
        ((float4*)&xs[r][0])[cc] = v;
    }
    __syncthreads();

    int ch = tid & 15, nl = tid >> 4;
    int node = node0 + nl;
    if (node >= n) return;
    float a1 = 0.f, a2 = 0.f;
    #pragma unroll
    for (int k = 0; k < INCH; ++k) {
        float xv = xs[nl][k];
        a1 += xv * Wc[k][ch];
        a2 += xv * Wc[k][ch + 16];
    }
    xW1s[node * C1 + ch] = a1 * inv[node];   // pre-scaled by inv[src]
    xT1[node * C1 + ch]  = a2 + t1b[ch];
}

// ---------------- agg1 CSR + fused epilogue1 (R5, proven) ------------------
__global__ __launch_bounds__(256) void agg1_csr_kernel(
    const int* __restrict__ sorted, const int* __restrict__ offs,
    const int* __restrict__ cnt, const float* __restrict__ inv,
    const float* __restrict__ xW1s, const float* __restrict__ xT1,
    const float* __restrict__ b1,
    float* __restrict__ h, float* __restrict__ hs, int n)
{
    int node = blockIdx.x * 16 + (threadIdx.x >> 4);
    int ch = threadIdx.x & 15;
    if (node >= n) return;
    int beg = offs[node], end = beg + cnt[node];
    float ic = inv[node];
    float a0 = 0.f, a1 = 0.f, a2 = 0.f, a3 = 0.f;
    int p = beg;
    for (; p + 3 < end; p += 4) {
        int s0 = sorted[p], s1 = sorted[p + 1], s2 = sorted[p + 2], s3 = sorted[p + 3];
        a0 += xW1s[s0 * C1 + ch];
        a1 += xW1s[s1 * C1 + ch];
        a2 += xW1s[s2 * C1 + ch];
        a3 += xW1s[s3 * C1 + ch];
    }
    for (; p < end; ++p) a0 += xW1s[sorted[p] * C1 + ch];
    int idx = node * C1 + ch;
    float v = (a0 + a1 + a2 + a3 + xW1s[idx]) * ic + b1[ch];
    float hv = fmaxf(v, 0.f) + xT1[idx];
    h[idx]  = hv;
    hs[idx] = hv * ic;
}

// ---------------- agg2 fused: CSR agg (16ch) + 16->64 linears + epi (R5) ---
__global__ __launch_bounds__(256) void agg2_fused_kernel(
    const int* __restrict__ sorted, const int* __restrict__ offs,
    const int* __restrict__ cnt, const float* __restrict__ inv,
    const float* __restrict__ hs, const float* __restrict__ h,
    const float* __restrict__ W2, const float* __restrict__ T2,
    const float* __restrict__ b2, const float* __restrict__ t2b,
    float* __restrict__ out, int n)
{
    __shared__ float Wc[C1][128];     // [:,0:64]=W2, [:,64:128]=t2_W
    __shared__ float acc_s[16][C1];   // aggregated (incl. self, *ic)
    __shared__ float h_s[16][C1];     // unscaled h for identity2
    int tid = threadIdx.x;

    for (int i = tid; i < C1 * 128; i += 256) {
        int k = i >> 7, c = i & 127;
        Wc[k][c] = (c < 64) ? W2[k * C2 + c] : T2[k * C2 + (c - 64)];
    }

    int nl = tid >> 4, ch = tid & 15;
    int node = blockIdx.x * 16 + nl;
    float acc = 0.f, hval = 0.f;
    if (node < n) {
        int beg = offs[node], end = beg + cnt[node];
        float a0 = 0.f, a1 = 0.f, a2 = 0.f, a3 = 0.f;
        int p = beg;
        for (; p + 3 < end; p += 4) {
            int s0 = sorted[p], s1 = sorted[p + 1], s2 = sorted[p + 2], s3 = sorted[p + 3];
            a0 += hs[s0 * C1 + ch];
            a1 += hs[s1 * C1 + ch];
            a2 += hs[s2 * C1 + ch];
            a3 += hs[s3 * C1 + ch];
        }
        for (; p < end; ++p) a0 += hs[sorted[p] * C1 + ch];
        int idx = node * C1 + ch;
        acc = (a0 + a1 + a2 + a3 + hs[idx]) * inv[node];
        hval = h[idx];
    }
    acc_s[nl][ch] = acc;
    h_s[nl][ch]   = hval;
    __syncthreads();

    int och = tid & 63, grp = tid >> 6;
    #pragma unroll
    for (int q = 0; q < 4; ++q) {
        int nl2 = grp * 4 + q;
        int node2 = blockIdx.x * 16 + nl2;
        if (node2 >= n) continue;
        float s1v = b2[och], s2v = t2b[och];
        #pragma unroll
        for (int k = 0; k < C1; ++k) {
            s1v += acc_s[nl2][k] * Wc[k][och];
            s2v += h_s[nl2][k]   * Wc[k][och + 64];
        }
        out[node2 * C2 + och] = fmaxf(s1v, 0.f) + s2v;
    }
}

extern "C" void kernel_launch(void* const* d_in, const int* in_sizes, int n_in,
                              void* d_out, int out_size, void* d_ws, size_t ws_size,
                              hipStream_t stream) {
    const float* x   = (const float*)d_in[0];
    const int*   ei  = (const int*)d_in[1];
    const float* W1  = (const float*)d_in[2];
    const float* b1  = (const float*)d_in[3];
    const float* W2  = (const float*)d_in[4];
    const float* b2  = (const float*)d_in[5];
    const float* T1  = (const float*)d_in[6];
    const float* t1b = (const float*)d_in[7];
    const float* T2  = (const float*)d_in[8];
    const float* t2b = (const float*)d_in[9];
    float* out = (float*)d_out;

    const int n = in_sizes[0] / INCH;       // 100000
    const int e = in_sizes[1] / 2;          // 3200000
    const int* row = ei;
    const int* col = ei + e;
    const int K = (n + BNODES - 1) >> LOCB; // 782 buckets

    // workspace layout — data-indexed buffers (sorted, barr) last
    char* ws = (char*)d_ws;
    int*   gcur  = (int*)ws;                          ws += 4096;
    int*   bbase = (int*)ws;                          ws += 4096;
    int*   cnt   = (int*)ws;                          ws += (size_t)n * 4;
    int*   offs  = (int*)ws;                          ws += (size_t)n * 4;
    float* inv   = (float*)ws;                        ws += (size_t)n * 4;
    float* xW1s  = (float*)ws;                        ws += (size_t)n * C1 * 4;
    float* xT1   = (float*)ws;                        ws += (size_t)n * C1 * 4;
    float* h     = (float*)ws;                        ws += (size_t)n * C1 * 4;
    float* hs    = (float*)ws;                        ws += (size_t)n * C1 * 4;
    int*   sorted= (int*)ws;                          ws += (size_t)e * 4;        // 12.8 MB
    int*   barr  = (int*)ws;                          ws += (size_t)K * CAP * 4;  // 16 MB

    const int B = 256;
    const int nbb = 390;     // bucket_kernel blocks

    binit_kernel      <<<(K + B - 1) / B, B, 0, stream>>>(gcur, K);
    bucket_kernel     <<<nbb, B, 0, stream>>>(row, col, gcur, barr, e, n, K, nbb);
    bucket_scan_kernel<<<1, 1024, 0, stream>>>(gcur, bbase, K);
    sort_kernel       <<<K, B, 0, stream>>>(barr, gcur, bbase, cnt, offs, inv, sorted, n);

    linear1_kernel <<<(n + 15) / 16, B, 0, stream>>>(x, W1, T1, t1b, inv, xW1s, xT1, n);
    agg1_csr_kernel<<<(n + 15) / 16, B, 0, stream>>>(sorted, offs, cnt, inv, xW1s, xT1, b1, h, hs, n);

    agg2_fused_kernel<<<(n + 15) / 16, B, 0, stream>>>(sorted, offs, cnt, inv, hs, h,
                                                       W2, T2, b2, t2b, out, n);
}

// Round 9
// 320.376 us; speedup vs baseline: 2.8252x; 1.0854x over previous
//
#include <hip/hip_runtime.h>

#define INCH 128
#define C1   16
#define C2   64
#define LOCB 7                   // log2(nodes per bucket)
#define BNODES (1 << LOCB)       // 128 nodes per bucket
#define CAP  5120                // edge capacity per bucket (mean 4096, +16 sigma)
#define ROWBITS 17
#define ROWMASK ((1 << ROWBITS) - 1)

// bf16 helpers: RTNE store, shift load
__device__ __forceinline__ unsigned short f2bf(float f) {
    unsigned u = __float_as_uint(f);
    return (unsigned short)((u + 0x7FFF + ((u >> 16) & 1)) >> 16);
}
__device__ __forceinline__ float bf2f(unsigned short s) {
    return __uint_as_float((unsigned)s << 16);
}

// ---------------- binit: gcur[b] = b*CAP -----------------------------------
__global__ void binit_kernel(int* __restrict__ gcur, int K) {
    int t = blockIdx.x * blockDim.x + threadIdx.x;
    if (t < K) gcur[t] = t * CAP;
}

// ---------------- bucket edges by dst range (R7, proven) -------------------
__global__ __launch_bounds__(256) void bucket_kernel(
    const int* __restrict__ row, const int* __restrict__ col,
    int* __restrict__ gcur, int* __restrict__ barr,
    int e, int n, int K, int nblocks)
{
    __shared__ int cnt[1024];
    __shared__ int cur[1024];
    long b0 = (long)blockIdx.x * e / nblocks;
    long b1 = (long)(blockIdx.x + 1) * e / nblocks;
    for (int i = threadIdx.x; i < 1024; i += 256) cnt[i] = 0;
    __syncthreads();
    for (long i = b0 + threadIdx.x; i < b1; i += 256) {
        unsigned c = (unsigned)col[i];
        unsigned r = (unsigned)row[i];
        if (c < (unsigned)n && r < (unsigned)n)
            atomicAdd(&cnt[c >> LOCB], 1);
    }
    __syncthreads();
    for (int i = threadIdx.x; i < K; i += 256) {
        int c = cnt[i];
        cur[i] = c ? atomicAdd(&gcur[i], c) : 0;
    }
    __syncthreads();
    for (long i = b0 + threadIdx.x; i < b1; i += 256) {
        unsigned c = (unsigned)col[i];
        unsigned r = (unsigned)row[i];
        if (c < (unsigned)n && r < (unsigned)n) {
            int b = c >> LOCB;
            int slot = atomicAdd(&cur[b], 1);        // LDS
            if ((unsigned)slot < (unsigned)((b + 1) * CAP))
                barr[slot] = (int)(r | ((c & (BNODES - 1)) << ROWBITS));
        }
    }
}

// ---------------- exclusive scan of bucket lengths -> bbase ----------------
__global__ __launch_bounds__(1024) void bucket_scan_kernel(
    const int* __restrict__ gcur, int* __restrict__ bbase, int K)
{
    __shared__ int tmp[1024];
    int t = threadIdx.x;
    int len = 0;
    if (t < K) {
        int l = gcur[t] - t * CAP;
        len = (l < 0) ? 0 : (l > CAP ? CAP : l);
    }
    tmp[t] = len;
    __syncthreads();
    for (int off = 1; off < 1024; off <<= 1) {
        int v = (t >= off) ? tmp[t - off] : 0;
        __syncthreads();
        tmp[t] += v;
        __syncthreads();
    }
    if (t < K) bbase[t] = tmp[t] - len;   // exclusive
}

// ---------------- per-bucket counting sort -> global CSR -------------------
__global__ __launch_bounds__(256) void sort_kernel(
    const int* __restrict__ barr, const int* __restrict__ gcur,
    const int* __restrict__ bbase,
    int* __restrict__ cnt, int* __restrict__ offs, float* __restrict__ inv,
    int* __restrict__ sorted, int n)
{
    __shared__ int lcnt[BNODES];
    __shared__ int lcur[BNODES];
    __shared__ int tmp[BNODES];
    int b = blockIdx.x;
    int tid = threadIdx.x;
    if (tid < BNODES) lcnt[tid] = 0;
    __syncthreads();
    int base = b * CAP;
    int len = gcur[b] - base;
    if (len < 0) len = 0;
    if (len > CAP) len = CAP;
    for (int i = tid; i < len; i += 256) {
        unsigned pk = (unsigned)barr[base + i];
        atomicAdd(&lcnt[(pk >> ROWBITS) & (BNODES - 1)], 1);
    }
    __syncthreads();
    int v = (tid < BNODES) ? lcnt[tid] : 0;
    if (tid < BNODES) tmp[tid] = v;
    __syncthreads();
    for (int off = 1; off < BNODES; off <<= 1) {
        int t2 = (tid < BNODES && tid >= off) ? tmp[tid - off] : 0;
        __syncthreads();
        if (tid < BNODES) tmp[tid] += t2;
        __syncthreads();
    }
    int gbase = bbase[b];
    if (tid < BNODES) {
        int exc = tmp[tid] - v;
        lcur[tid] = exc;
        int node = (b << LOCB) + tid;
        if (node < n) {
            cnt[node]  = v;
            offs[node] = gbase + exc;
            inv[node]  = rsqrtf((float)(v + 1));
        }
    }
    __syncthreads();
    for (int i = tid; i < len; i += 256) {
        unsigned pk = (unsigned)barr[base + i];
        int loc = (pk >> ROWBITS) & (BNODES - 1);
        int pos = atomicAdd(&lcur[loc], 1);          // LDS
        if ((unsigned)pos < (unsigned)(CAP * 782u))
            sorted[gbase + pos] = (int)(pk & ROWMASK);
    }
}

// ---------------- linear1: xW1s_bf = bf16((x@W1)*inv), xT1 = x@t1_W + t1_b -
__global__ __launch_bounds__(256) void linear1_kernel(
    const float* __restrict__ x, const float* __restrict__ W1,
    const float* __restrict__ T1, const float* __restrict__ t1b,
    const float* __restrict__ inv,
    unsigned short* __restrict__ xW1s_bf, float* __restrict__ xT1, int n)
{
    __shared__ float Wc[INCH][32];        // [:,0:16]=W1, [:,16:32]=t1_W
    __shared__ float xs[16][INCH + 4];
    int tid = threadIdx.x;

    for (int i = tid; i < INCH * C1; i += 256) {
        int k = i / C1, c = i % C1;
        Wc[k][c]      = W1[i];
        Wc[k][c + 16] = T1[i];
    }
    int node0 = blockIdx.x * 16;
    for (int i = tid; i < 16 * (INCH / 4); i += 256) {
        int r = i / (INCH / 4);
        int cc = i % (INCH / 4);
        int node = node0 + r;
        float4 v = make_float4(0.f, 0.f, 0.f, 0.f);
        if (node < n) v = ((const float4*)x)[(size_t)node * (INCH / 4) + cc];
        ((float4*)&xs[r][0])[cc] = v;
    }
    __syncthreads();

    int ch = tid & 15, nl = tid >> 4;
    int node = node0 + nl;
    if (node >= n) return;
    float a1 = 0.f, a2 = 0.f;
    #pragma unroll
    for (int k = 0; k < INCH; ++k) {
        float xv = xs[nl][k];
        a1 += xv * Wc[k][ch];
        a2 += xv * Wc[k][ch + 16];
    }
    xW1s_bf[(node << 4) + ch] = f2bf(a1 * inv[node]);  // pre-scaled by inv[src]
    xT1[(node << 4) + ch]     = a2 + t1b[ch];
}

// ---------------- agg1 CSR (bf16 gathers) + fused epilogue1 ----------------
__global__ __launch_bounds__(256) void agg1_csr_kernel(
    const int* __restrict__ sorted, const int* __restrict__ offs,
    const int* __restrict__ cnt, const float* __restrict__ inv,
    const unsigned short* __restrict__ xW1s_bf, const float* __restrict__ xT1,
    const float* __restrict__ b1,
    float* __restrict__ h, unsigned short* __restrict__ hs_bf, int n)
{
    int node = blockIdx.x * 16 + (threadIdx.x >> 4);
    int ch = threadIdx.x & 15;
    if (node >= n) return;
    int beg = offs[node], end = beg + cnt[node];
    float ic = inv[node];
    float a0 = 0.f, a1 = 0.f, a2 = 0.f, a3 = 0.f;
    int p = beg;
    for (; p + 7 < end; p += 8) {          // 8 gathers in flight
        int s0 = sorted[p],     s1 = sorted[p + 1];
        int s2 = sorted[p + 2], s3 = sorted[p + 3];
        int s4 = sorted[p + 4], s5 = sorted[p + 5];
        int s6 = sorted[p + 6], s7 = sorted[p + 7];
        a0 += bf2f(xW1s_bf[(s0 << 4) + ch]);
        a1 += bf2f(xW1s_bf[(s1 << 4) + ch]);
        a2 += bf2f(xW1s_bf[(s2 << 4) + ch]);
        a3 += bf2f(xW1s_bf[(s3 << 4) + ch]);
        a0 += bf2f(xW1s_bf[(s4 << 4) + ch]);
        a1 += bf2f(xW1s_bf[(s5 << 4) + ch]);
        a2 += bf2f(xW1s_bf[(s6 << 4) + ch]);
        a3 += bf2f(xW1s_bf[(s7 << 4) + ch]);
    }
    for (; p < end; ++p) a0 += bf2f(xW1s_bf[(sorted[p] << 4) + ch]);
    int idx = (node << 4) + ch;
    float v = (a0 + a1 + a2 + a3 + bf2f(xW1s_bf[idx])) * ic + b1[ch];
    float hv = fmaxf(v, 0.f) + xT1[idx];
    h[idx]     = hv;
    hs_bf[idx] = f2bf(hv * ic);
}

// ---------------- agg2 fused: bf16 CSR agg + 16->64 linears + epilogue -----
__global__ __launch_bounds__(256) void agg2_fused_kernel(
    const int* __restrict__ sorted, const int* __restrict__ offs,
    const int* __restrict__ cnt, const float* __restrict__ inv,
    const unsigned short* __restrict__ hs_bf, const float* __restrict__ h,
    const float* __restrict__ W2, const float* __restrict__ T2,
    const float* __restrict__ b2, const float* __restrict__ t2b,
    float* __restrict__ out, int n)
{
    __shared__ float Wc[C1][128];     // [:,0:64]=W2, [:,64:128]=t2_W
    __shared__ float acc_s[16][C1];   // aggregated (incl. self, *ic)
    __shared__ float h_s[16][C1];     // unscaled h for identity2
    int tid = threadIdx.x;

    for (int i = tid; i < C1 * 128; i += 256) {
        int k = i >> 7, c = i & 127;
        Wc[k][c] = (c < 64) ? W2[k * C2 + c] : T2[k * C2 + (c - 64)];
    }

    int nl = tid >> 4, ch = tid & 15;
    int node = blockIdx.x * 16 + nl;
    float acc = 0.f, hval = 0.f;
    if (node < n) {
        int beg = offs[node], end = beg + cnt[node];
        float a0 = 0.f, a1 = 0.f, a2 = 0.f, a3 = 0.f;
        int p = beg;
        for (; p + 7 < end; p += 8) {
            int s0 = sorted[p],     s1 = sorted[p + 1];
            int s2 = sorted[p + 2], s3 = sorted[p + 3];
            int s4 = sorted[p + 4], s5 = sorted[p + 5];
            int s6 = sorted[p + 6], s7 = sorted[p + 7];
            a0 += bf2f(hs_bf[(s0 << 4) + ch]);
            a1 += bf2f(hs_bf[(s1 << 4) + ch]);
            a2 += bf2f(hs_bf[(s2 << 4) + ch]);
            a3 += bf2f(hs_bf[(s3 << 4) + ch]);
            a0 += bf2f(hs_bf[(s4 << 4) + ch]);
            a1 += bf2f(hs_bf[(s5 << 4) + ch]);
            a2 += bf2f(hs_bf[(s6 << 4) + ch]);
            a3 += bf2f(hs_bf[(s7 << 4) + ch]);
        }
        for (; p < end; ++p) a0 += bf2f(hs_bf[(sorted[p] << 4) + ch]);
        int idx = (node << 4) + ch;
        acc = (a0 + a1 + a2 + a3 + bf2f(hs_bf[idx])) * inv[node];
        hval = h[idx];
    }
    acc_s[nl][ch] = acc;
    h_s[nl][ch]   = hval;
    __syncthreads();

    int och = tid & 63, grp = tid >> 6;
    #pragma unroll
    for (int q = 0; q < 4; ++q) {
        int nl2 = grp * 4 + q;
        int node2 = blockIdx.x * 16 + nl2;
        if (node2 >= n) continue;
        float s1v = b2[och], s2v = t2b[och];
        #pragma unroll
        for (int k = 0; k < C1; ++k) {
            s1v += acc_s[nl2][k] * Wc[k][och];
            s2v += h_s[nl2][k]   * Wc[k][och + 64];
        }
        out[node2 * C2 + och] = fmaxf(s1v, 0.f) + s2v;
    }
}

extern "C" void kernel_launch(void* const* d_in, const int* in_sizes, int n_in,
                              void* d_out, int out_size, void* d_ws, size_t ws_size,
                              hipStream_t stream) {
    const float* x   = (const float*)d_in[0];
    const int*   ei  = (const int*)d_in[1];
    const float* W1  = (const float*)d_in[2];
    const float* b1  = (const float*)d_in[3];
    const float* W2  = (const float*)d_in[4];
    const float* b2  = (const float*)d_in[5];
    const float* T1  = (const float*)d_in[6];
    const float* t1b = (const float*)d_in[7];
    const float* T2  = (const float*)d_in[8];
    const float* t2b = (const float*)d_in[9];
    float* out = (float*)d_out;

    const int n = in_sizes[0] / INCH;       // 100000
    const int e = in_sizes[1] / 2;          // 3200000
    const int* row = ei;
    const int* col = ei + e;
    const int K = (n + BNODES - 1) >> LOCB; // 782 buckets

    // workspace layout — data-indexed buffers (sorted, barr) last
    char* ws = (char*)d_ws;
    int*   gcur  = (int*)ws;                          ws += 4096;
    int*   bbase = (int*)ws;                          ws += 4096;
    int*   cnt   = (int*)ws;                          ws += (size_t)n * 4;
    int*   offs  = (int*)ws;                          ws += (size_t)n * 4;
    float* inv   = (float*)ws;                        ws += (size_t)n * 4;
    float* xT1   = (float*)ws;                        ws += (size_t)n * C1 * 4;
    float* h     = (float*)ws;                        ws += (size_t)n * C1 * 4;
    unsigned short* xW1s_bf = (unsigned short*)ws;    ws += (size_t)n * C1 * 2;  // 3.2 MB
    unsigned short* hs_bf   = (unsigned short*)ws;    ws += (size_t)n * C1 * 2;  // 3.2 MB
    int*   sorted= (int*)ws;                          ws += (size_t)e * 4;       // 12.8 MB
    int*   barr  = (int*)ws;                          ws += (size_t)K * CAP * 4; // 16 MB

    const int B = 256;
    const int nbb = 390;     // bucket_kernel blocks

    binit_kernel      <<<(K + B - 1) / B, B, 0, stream>>>(gcur, K);
    bucket_kernel     <<<nbb, B, 0, stream>>>(row, col, gcur, barr, e, n, K, nbb);
    bucket_scan_kernel<<<1, 1024, 0, stream>>>(gcur, bbase, K);
    sort_kernel       <<<K, B, 0, stream>>>(barr, gcur, bbase, cnt, offs, inv, sorted, n);

    linear1_kernel <<<(n + 15) / 16, B, 0, stream>>>(x, W1, T1, t1b, inv, xW1s_bf, xT1, n);
    agg1_csr_kernel<<<(n + 15) / 16, B, 0, stream>>>(sorted, offs, cnt, inv, xW1s_bf, xT1, b1, h, hs_bf, n);

    agg2_fused_kernel<<<(n + 15) / 16, B, 0, stream>>>(sorted, offs, cnt, inv, hs_bf, h,
                                                       W2, T2, b2, t2b, out, n);
}

// Round 10
// 299.924 us; speedup vs baseline: 3.0178x; 1.0682x over previous
//
#include <hip/hip_runtime.h>

#define INCH 128
#define C1   16
#define C2   64
#define LOCB 7                   // log2(nodes per bucket)
#define BNODES (1 << LOCB)       // 128 nodes per bucket
#define CAP  8192                // padded edge capacity per bucket (mean ~6240 padded)
#define ROWBITS 17
#define ROWMASK ((1 << ROWBITS) - 1)
#define SENT 0xFFFFFFFFu         // sentinel: src field = 0x1FFFF >= n -> filtered

typedef int iv4 __attribute__((ext_vector_type(4)));

// bf16 helpers: RTNE store, shift load
__device__ __forceinline__ unsigned short f2bf(float f) {
    unsigned u = __float_as_uint(f);
    return (unsigned short)((u + 0x7FFF + ((u >> 16) & 1)) >> 16);
}
__device__ __forceinline__ float bf2f(unsigned short s) {
    return __uint_as_float((unsigned)s << 16);
}

// ---------------- binit: gcur[b] = b*CAP -----------------------------------
__global__ void binit_kernel(int* __restrict__ gcur, int K) {
    int t = blockIdx.x * blockDim.x + threadIdx.x;
    if (t < K) gcur[t] = t * CAP;
}

// ---------------- bucket edges, line-aligned padded reservations -----------
// Reservation rounded to 16 edges (64 B): each barr line has exactly one
// writer block and is fully written (pad = SENT) -> no partial-line
// write-back, no cross-XCD line sharing. Per-edge RMWs stay in LDS.
__global__ __launch_bounds__(256) void bucket_kernel(
    const int* __restrict__ row, const int* __restrict__ col,
    int* __restrict__ gcur, int* __restrict__ barr,
    int e, int n, int K, int nblocks)
{
    __shared__ int cnt[1024];     // valid count per bucket
    __shared__ int cur[1024];     // write cursor
    __shared__ int sst[1024];     // chunk start
    int e4 = e >> 2;
    long b0 = (long)blockIdx.x * e4 / nblocks;
    long b1 = (long)(blockIdx.x + 1) * e4 / nblocks;
    const iv4* c4p = (const iv4*)col;
    const iv4* r4p = (const iv4*)row;
    for (int i = threadIdx.x; i < 1024; i += 256) cnt[i] = 0;
    __syncthreads();
    for (long i = b0 + threadIdx.x; i < b1; i += 256) {
        iv4 c4 = c4p[i], r4 = r4p[i];
        #pragma unroll
        for (int k = 0; k < 4; ++k) {
            unsigned c = (unsigned)c4[k], r = (unsigned)r4[k];
            if (c < (unsigned)n && r < (unsigned)n)
                atomicAdd(&cnt[c >> LOCB], 1);
        }
    }
    if (blockIdx.x == 0) {
        for (int i = e4 * 4 + threadIdx.x; i < e; i += 256) {
            unsigned c = (unsigned)col[i], r = (unsigned)row[i];
            if (c < (unsigned)n && r < (unsigned)n)
                atomicAdd(&cnt[c >> LOCB], 1);
        }
    }
    __syncthreads();
    for (int i = threadIdx.x; i < K; i += 256) {
        int c = cnt[i];
        int start = c ? atomicAdd(&gcur[i], (c + 15) & ~15) : 0;
        cur[i] = start;
        sst[i] = start;
    }
    __syncthreads();
    for (long i = b0 + threadIdx.x; i < b1; i += 256) {
        iv4 c4 = c4p[i], r4 = r4p[i];
        #pragma unroll
        for (int k = 0; k < 4; ++k) {
            unsigned c = (unsigned)c4[k], r = (unsigned)r4[k];
            if (c < (unsigned)n && r < (unsigned)n) {
                int b = c >> LOCB;
                int slot = atomicAdd(&cur[b], 1);          // LDS
                if ((unsigned)slot < (unsigned)((b + 1) * CAP))
                    barr[slot] = (int)(r | ((c & (BNODES - 1)) << ROWBITS));
            }
        }
    }
    if (blockIdx.x == 0) {
        for (int i = e4 * 4 + threadIdx.x; i < e; i += 256) {
            unsigned c = (unsigned)col[i], r = (unsigned)row[i];
            if (c < (unsigned)n && r < (unsigned)n) {
                int b = c >> LOCB;
                int slot = atomicAdd(&cur[b], 1);
                if ((unsigned)slot < (unsigned)((b + 1) * CAP))
                    barr[slot] = (int)(r | ((c & (BNODES - 1)) << ROWBITS));
            }
        }
    }
    __syncthreads();
    // sentinel-fill the pad so every reserved line is fully written
    for (int i = threadIdx.x; i < K; i += 256) {
        int c = cnt[i];
        if (!c) continue;
        int start = sst[i];
        int end = start + c;
        int re  = start + ((c + 15) & ~15);
        int lim = (i + 1) * CAP;
        if (end > lim) end = lim;
        if (re  > lim) re  = lim;
        for (int j = end; j < re; ++j) barr[j] = (int)SENT;
    }
}

// ---------------- exclusive scan of padded bucket lengths -> bbase ---------
__global__ __launch_bounds__(1024) void bucket_scan_kernel(
    const int* __restrict__ gcur, int* __restrict__ bbase, int K)
{
    __shared__ int tmp[1024];
    int t = threadIdx.x;
    int len = 0;
    if (t < K) {
        int l = gcur[t] - t * CAP;
        len = (l < 0) ? 0 : (l > CAP ? CAP : l);
    }
    tmp[t] = len;
    __syncthreads();
    for (int off = 1; off < 1024; off <<= 1) {
        int v = (t >= off) ? tmp[t - off] : 0;
        __syncthreads();
        tmp[t] += v;
        __syncthreads();
    }
    if (t < K) bbase[t] = tmp[t] - len;   // exclusive
}

// ---------------- per-bucket counting sort -> global CSR -------------------
// One block per bucket; sentinels (src >= n) skipped. sorted is packed
// densely within each bucket starting at bbase[b] (inter-bucket gaps ok).
__global__ __launch_bounds__(256) void sort_kernel(
    const int* __restrict__ barr, const int* __restrict__ gcur,
    const int* __restrict__ bbase,
    int* __restrict__ cnt, int* __restrict__ offs, float* __restrict__ inv,
    int* __restrict__ sorted, int n)
{
    __shared__ int lcnt[BNODES];
    __shared__ int lcur[BNODES];
    __shared__ int tmp[BNODES];
    int b = blockIdx.x;
    int tid = threadIdx.x;
    if (tid < BNODES) lcnt[tid] = 0;
    __syncthreads();
    int base = b * CAP;
    int len = gcur[b] - base;
    if (len < 0) len = 0;
    if (len > CAP) len = CAP;
    int len4 = len >> 2;
    const iv4* b4 = (const iv4*)(barr + base);
    for (int i = tid; i < len4; i += 256) {
        iv4 p4 = b4[i];
        #pragma unroll
        for (int k = 0; k < 4; ++k) {
            unsigned pk = (unsigned)p4[k];
            if ((pk & ROWMASK) < (unsigned)n)
                atomicAdd(&lcnt[(pk >> ROWBITS) & (BNODES - 1)], 1);
        }
    }
    for (int i = len4 * 4 + tid; i < len; i += 256) {       // safety tail
        unsigned pk = (unsigned)barr[base + i];
        if ((pk & ROWMASK) < (unsigned)n)
            atomicAdd(&lcnt[(pk >> ROWBITS) & (BNODES - 1)], 1);
    }
    __syncthreads();
    int v = (tid < BNODES) ? lcnt[tid] : 0;
    if (tid < BNODES) tmp[tid] = v;
    __syncthreads();
    for (int off = 1; off < BNODES; off <<= 1) {
        int t2 = (tid < BNODES && tid >= off) ? tmp[tid - off] : 0;
        __syncthreads();
        if (tid < BNODES) tmp[tid] += t2;
        __syncthreads();
    }
    int gbase = bbase[b];
    if (tid < BNODES) {
        int exc = tmp[tid] - v;
        lcur[tid] = exc;
        int node = (b << LOCB) + tid;
        if (node < n) {
            cnt[node]  = v;
            offs[node] = gbase + exc;
            inv[node]  = rsqrtf((float)(v + 1));
        }
    }
    __syncthreads();
    for (int i = tid; i < len4; i += 256) {
        iv4 p4 = b4[i];
        #pragma unroll
        for (int k = 0; k < 4; ++k) {
            unsigned pk = (unsigned)p4[k];
            if ((pk & ROWMASK) < (unsigned)n) {
                int loc = (pk >> ROWBITS) & (BNODES - 1);
                int pos = atomicAdd(&lcur[loc], 1);          // LDS
                if ((unsigned)pos < (unsigned)CAP)
                    sorted[gbase + pos] = (int)(pk & ROWMASK);
            }
        }
    }
    for (int i = len4 * 4 + tid; i < len; i += 256) {
        unsigned pk = (unsigned)barr[base + i];
        if ((pk & ROWMASK) < (unsigned)n) {
            int loc = (pk >> ROWBITS) & (BNODES - 1);
            int pos = atomicAdd(&lcur[loc], 1);
            if ((unsigned)pos < (unsigned)CAP)
                sorted[gbase + pos] = (int)(pk & ROWMASK);
        }
    }
}

// ---------------- linear1: xW1s_bf = bf16((x@W1)*inv), xT1 = x@t1_W + t1_b -
__global__ __launch_bounds__(256) void linear1_kernel(
    const float* __restrict__ x, const float* __restrict__ W1,
    const float* __restrict__ T1, const float* __restrict__ t1b,
    const float* __restrict__ inv,
    unsigned short* __restrict__ xW1s_bf, float* __restrict__ xT1, int n)
{
    __shared__ float Wc[INCH][32];        // [:,0:16]=W1, [:,16:32]=t1_W
    __shared__ float xs[16][INCH + 4];
    int tid = threadIdx.x;

    for (int i = tid; i < INCH * C1; i += 256) {
        int k = i / C1, c = i % C1;
        Wc[k][c]      = W1[i];
        Wc[k][c + 16] = T1[i];
    }
    int node0 = blockIdx.x * 16;
    for (int i = tid; i < 16 * (INCH / 4); i += 256) {
        int r = i / (INCH / 4);
        int cc = i % (INCH / 4);
        int node = node0 + r;
        float4 v = make_float4(0.f, 0.f, 0.f, 0.f);
        if (node < n) v = ((const float4*)x)[(size_t)node * (INCH / 4) + cc];
        ((float4*)&xs[r][0])[cc] = v;
    }
    __syncthreads();

    int ch = tid & 15, nl = tid >> 4;
    int node = node0 + nl;
    if (node >= n) return;
    float a1 = 0.f, a2 = 0.f;
    #pragma unroll
    for (int k = 0; k < INCH; ++k) {
        float xv = xs[nl][k];
        a1 += xv * Wc[k][ch];
        a2 += xv * Wc[k][ch + 16];
    }
    xW1s_bf[(node << 4) + ch] = f2bf(a1 * inv[node]);  // pre-scaled by inv[src]
    xT1[(node << 4) + ch]     = a2 + t1b[ch];
}

// ---------------- agg1 CSR (bf16 gathers) + fused epilogue1 ----------------
__global__ __launch_bounds__(256) void agg1_csr_kernel(
    const int* __restrict__ sorted, const int* __restrict__ offs,
    const int* __restrict__ cnt, const float* __restrict__ inv,
    const unsigned short* __restrict__ xW1s_bf, const float* __restrict__ xT1,
    const float* __restrict__ b1,
    float* __restrict__ h, unsigned short* __restrict__ hs_bf, int n)
{
    int node = blockIdx.x * 16 + (threadIdx.x >> 4);
    int ch = threadIdx.x & 15;
    if (node >= n) return;
    int beg = offs[node], end = beg + cnt[node];
    float ic = inv[node];
    float a0 = 0.f, a1 = 0.f, a2 = 0.f, a3 = 0.f;
    int p = beg;
    for (; p + 7 < end; p += 8) {          // 8 gathers in flight
        int s0 = sorted[p],     s1 = sorted[p + 1];
        int s2 = sorted[p + 2], s3 = sorted[p + 3];
        int s4 = sorted[p + 4], s5 = sorted[p + 5];
        int s6 = sorted[p + 6], s7 = sorted[p + 7];
        a0 += bf2f(xW1s_bf[(s0 << 4) + ch]);
        a1 += bf2f(xW1s_bf[(s1 << 4) + ch]);
        a2 += bf2f(xW1s_bf[(s2 << 4) + ch]);
        a3 += bf2f(xW1s_bf[(s3 << 4) + ch]);
        a0 += bf2f(xW1s_bf[(s4 << 4) + ch]);
        a1 += bf2f(xW1s_bf[(s5 << 4) + ch]);
        a2 += bf2f(xW1s_bf[(s6 << 4) + ch]);
        a3 += bf2f(xW1s_bf[(s7 << 4) + ch]);
    }
    for (; p < end; ++p) a0 += bf2f(xW1s_bf[(sorted[p] << 4) + ch]);
    int idx = (node << 4) + ch;
    float v = (a0 + a1 + a2 + a3 + bf2f(xW1s_bf[idx])) * ic + b1[ch];
    float hv = fmaxf(v, 0.f) + xT1[idx];
    h[idx]     = hv;
    hs_bf[idx] = f2bf(hv * ic);
}

// ---------------- agg2 fused: bf16 CSR agg + 16->64 linears + epilogue -----
__global__ __launch_bounds__(256) void agg2_fused_kernel(
    const int* __restrict__ sorted, const int* __restrict__ offs,
    const int* __restrict__ cnt, const float* __restrict__ inv,
    const unsigned short* __restrict__ hs_bf, const float* __restrict__ h,
    const float* __restrict__ W2, const float* __restrict__ T2,
    const float* __restrict__ b2, const float* __restrict__ t2b,
    float* __restrict__ out, int n)
{
    __shared__ float Wc[C1][128];     // [:,0:64]=W2, [:,64:128]=t2_W
    __shared__ float acc_s[16][C1];   // aggregated (incl. self, *ic)
    __shared__ float h_s[16][C1];     // unscaled h for identity2
    int tid = threadIdx.x;

    for (int i = tid; i < C1 * 128; i += 256) {
        int k = i >> 7, c = i & 127;
        Wc[k][c] = (c < 64) ? W2[k * C2 + c] : T2[k * C2 + (c - 64)];
    }

    int nl = tid >> 4, ch = tid & 15;
    int node = blockIdx.x * 16 + nl;
    float acc = 0.f, hval = 0.f;
    if (node < n) {
        int beg = offs[node], end = beg + cnt[node];
        float a0 = 0.f, a1 = 0.f, a2 = 0.f, a3 = 0.f;
        int p = beg;
        for (; p + 7 < end; p += 8) {
            int s0 = sorted[p],     s1 = sorted[p + 1];
            int s2 = sorted[p + 2], s3 = sorted[p + 3];
            int s4 = sorted[p + 4], s5 = sorted[p + 5];
            int s6 = sorted[p + 6], s7 = sorted[p + 7];
            a0 += bf2f(hs_bf[(s0 << 4) + ch]);
            a1 += bf2f(hs_bf[(s1 << 4) + ch]);
            a2 += bf2f(hs_bf[(s2 << 4) + ch]);
            a3 += bf2f(hs_bf[(s3 << 4) + ch]);
            a0 += bf2f(hs_bf[(s4 << 4) + ch]);
            a1 += bf2f(hs_bf[(s5 << 4) + ch]);
            a2 += bf2f(hs_bf[(s6 << 4) + ch]);
            a3 += bf2f(hs_bf[(s7 << 4) + ch]);
        }
        for (; p < end; ++p) a0 += bf2f(hs_bf[(sorted[p] << 4) + ch]);
        int idx = (node << 4) + ch;
        acc = (a0 + a1 + a2 + a3 + bf2f(hs_bf[idx])) * inv[node];
        hval = h[idx];
    }
    acc_s[nl][ch] = acc;
    h_s[nl][ch]   = hval;
    __syncthreads();

    int och = tid & 63, grp = tid >> 6;
    #pragma unroll
    for (int q = 0; q < 4; ++q) {
        int nl2 = grp * 4 + q;
        int node2 = blockIdx.x * 16 + nl2;
        if (node2 >= n) continue;
        float s1v = b2[och], s2v = t2b[och];
        #pragma unroll
        for (int k = 0; k < C1; ++k) {
            s1v += acc_s[nl2][k] * Wc[k][och];
            s2v += h_s[nl2][k]   * Wc[k][och + 64];
        }
        out[node2 * C2 + och] = fmaxf(s1v, 0.f) + s2v;
    }
}

extern "C" void kernel_launch(void* const* d_in, const int* in_sizes, int n_in,
                              void* d_out, int out_size, void* d_ws, size_t ws_size,
                              hipStream_t stream) {
    const float* x   = (const float*)d_in[0];
    const int*   ei  = (const int*)d_in[1];
    const float* W1  = (const float*)d_in[2];
    const float* b1  = (const float*)d_in[3];
    const float* W2  = (const float*)d_in[4];
    const float* b2  = (const float*)d_in[5];
    const float* T1  = (const float*)d_in[6];
    const float* t1b = (const float*)d_in[7];
    const float* T2  = (const float*)d_in[8];
    const float* t2b = (const float*)d_in[9];
    float* out = (float*)d_out;

    const int n = in_sizes[0] / INCH;       // 100000
    const int e = in_sizes[1] / 2;          // 3200000
    const int* row = ei;
    const int* col = ei + e;
    const int K = (n + BNODES - 1) >> LOCB; // 782 buckets

    // workspace layout — data-indexed buffers (sorted, barr) last
    char* ws = (char*)d_ws;
    int*   gcur  = (int*)ws;                          ws += 4096;
    int*   bbase = (int*)ws;                          ws += 4096;
    int*   cnt   = (int*)ws;                          ws += (size_t)n * 4;
    int*   offs  = (int*)ws;                          ws += (size_t)n * 4;
    float* inv   = (float*)ws;                        ws += (size_t)n * 4;
    float* xT1   = (float*)ws;                        ws += (size_t)n * C1 * 4;
    float* h     = (float*)ws;                        ws += (size_t)n * C1 * 4;
    unsigned short* xW1s_bf = (unsigned short*)ws;    ws += (size_t)n * C1 * 2;  // 3.2 MB
    unsigned short* hs_bf   = (unsigned short*)ws;    ws += (size_t)n * C1 * 2;  // 3.2 MB
    int*   sorted= (int*)ws;                          ws += (size_t)K * CAP * 4; // 25.6 MB
    int*   barr  = (int*)ws;                          ws += (size_t)K * CAP * 4; // 25.6 MB

    const int B = 256;
    const int nbb = 390;     // bucket_kernel blocks

    binit_kernel      <<<(K + B - 1) / B, B, 0, stream>>>(gcur, K);
    bucket_kernel     <<<nbb, B, 0, stream>>>(row, col, gcur, barr, e, n, K, nbb);
    bucket_scan_kernel<<<1, 1024, 0, stream>>>(gcur, bbase, K);
    sort_kernel       <<<K, B, 0, stream>>>(barr, gcur, bbase, cnt, offs, inv, sorted, n);

    linear1_kernel <<<(n + 15) / 16, B, 0, stream>>>(x, W1, T1, t1b, inv, xW1s_bf, xT1, n);
    agg1_csr_kernel<<<(n + 15) / 16, B, 0, stream>>>(sorted, offs, cnt, inv, xW1s_bf, xT1, b1, h, hs_bf, n);

    agg2_fused_kernel<<<(n + 15) / 16, B, 0, stream>>>(sorted, offs, cnt, inv, hs_bf, h,
                                                       W2, T2, b2, t2b, out, n);
}